// Round 8
// baseline (3692.527 us; speedup 1.0000x reference)
//
#include <hip/hip_runtime.h>
#include <math.h>

#define E 256
#define Hh 512

typedef __attribute__((ext_vector_type(8))) short short8;
typedef __attribute__((ext_vector_type(4))) float f32x4;
typedef __attribute__((ext_vector_type(4))) unsigned uint4v;

// R20: halve BOTH HBM streams identified in R19's FETCH itemization.
// (a) staging bytes = N_rows x 1KB x GROUP_SIZE -> groups of 4 (j-tile 128),
//     grid 168, acc[2][4][2], 384 MFMA/wave/step.
// (b) emb gather: bf16 emb tables cvt'd in prologue (ws-guarded; f32 fallback
//     via template) -> half bytes, half gathers (fewer blocks), no cvt8 VALU.
// Coherent dwordx4 sc0 sc1 exchange, swizzles, counter protocol (target 4t),
// gate-per-lane in-register epilogue: verbatim R19 (proven 3.05e-5).

struct LstmP {
  const int* ids;
  const float* emb;            // f32 embedding table (fallback path)
  const unsigned short* embb;  // bf16 embedding table (fast path; may be null)
  const unsigned short* Wih;   // bf16 ws cache [2048,256]
  const unsigned short* Whh;   // bf16 ws cache [2048,512]
  const float* bias;           // f32 [2048]
  unsigned short* h0;          // bf16 double buffer base (2 * nh)
  float* c;                    // f32 [N,512] final-c output
  int T;
  int nh;                      // N*512
};

__device__ unsigned g_cnt[42*32];   // per-group step counters, 128B apart

__device__ __forceinline__ float bf2f(unsigned short x){
  union { unsigned u; float f; } v; v.u = ((unsigned)x) << 16; return v.f;
}
__device__ __forceinline__ unsigned short f2bf(float f){
  union { float f; unsigned u; } v; v.f = f;
  unsigned u = v.u;
  return (unsigned short)((u + 0x7fffu + ((u >> 16) & 1u)) >> 16);
}
__device__ __forceinline__ short8 cvt8(const float* p){
  f32x4 x = *(const f32x4*)p;
  f32x4 y = *(const f32x4*)(p + 4);
  short8 r;
  r[0]=(short)f2bf(x[0]); r[1]=(short)f2bf(x[1]); r[2]=(short)f2bf(x[2]); r[3]=(short)f2bf(x[3]);
  r[4]=(short)f2bf(y[0]); r[5]=(short)f2bf(y[1]); r[6]=(short)f2bf(y[2]); r[7]=(short)f2bf(y[3]);
  return r;
}
// Fast activations (R18-proven): v_exp_f32/v_rcp_f32, ~1e-7/step, << threshold.
__device__ __forceinline__ float sigm(float x){
  return __builtin_amdgcn_rcpf(1.0f + __builtin_amdgcn_exp2f(-1.44269504f*x));
}
__device__ __forceinline__ float tanh_f(float x){
  return 1.0f - 2.0f*__builtin_amdgcn_rcpf(1.0f + __builtin_amdgcn_exp2f(2.88539008f*x));
}

__global__ void zero_ws_kernel(uint4* p, int n){
  int i = blockIdx.x*256 + threadIdx.x;
  if (i < n){ uint4 z; z.x=0u; z.y=0u; z.z=0u; z.w=0u; p[i]=z; }
}

__global__ void zero_cnt_kernel(){
  for (int i = threadIdx.x; i < 42*32; i += 256) g_cnt[i] = 0u;
}

// f32 -> bf16 (RNE), 8 elems/thread. (R3-proven cache bit-match.)
__global__ __launch_bounds__(256) void cvt_kernel(const float* src, unsigned short* dst, int n8){
  int i = blockIdx.x*256 + threadIdx.x;
  if (i < n8){
    *(short8*)(dst + (size_t)i*8) = cvt8(src + (size_t)i*8);
  }
}

// Persistent kernel: block = one (lstm, mb32, jt128) tile for all T steps.
// Per step: group wait -> issue 8x16B coherent h loads (regs) -> phase1
// (emb x Wih, loads in flight) -> vmcnt(0) -> LDS deposit -> phase2 (h x Whh)
// -> in-register epilogue -> 16B coherent h stores -> drain -> barrier -> release.
template<int EBF>
__global__ __launch_bounds__(256, 2) void lstm_persist(LstmP sc, LstmP cm, LstmP is_)
{
  __shared__ unsigned short hs[32][512];    // 32 KB staged h slab (swizzled)
  __shared__ unsigned short sh_h[32][136];  // h shuttle, padded rows (272B, 16B-aligned)

  LstmP P; int tile, grp;
  {
    int idx = blockIdx.x;
    if (idx < 80){ P = sc;  tile = idx;        grp = tile >> 2; }
    else if (idx < 160){ P = cm;  tile = idx - 80;   grp = 20 + (tile >> 2); }
    else { P = is_; tile = idx - 160;  grp = 40 + (tile >> 2); }
  }
  const int tid  = threadIdx.x;
  const int w    = tid >> 6;       // wave = 32-wide j-subslice owner (all 4 gates)
  const int lane = tid & 63;
  const int l15  = lane & 15;
  const int q    = lane >> 4;
  const int mb = tile >> 2, jt = tile & 3;
  const int m0 = mb*32, j0 = jt*128;
  const int jw = j0 + w*32;
  const int T = P.T;
  unsigned* cgp = &g_cnt[grp*32];
  const int xr = (l15 & 7) << 3;   // hs row-XOR swizzle (per-lane const, in shorts)

  const int* idrow[2];             // ids row per A-fragment row
  #pragma unroll
  for (int mi=0; mi<2; ++mi){
    int m = m0 + mi*16 + l15;
    idrow[mi] = P.ids + (size_t)m*T;
  }
  // Weight base pointers: gate g, unit jw+l15 (ni adds 16 rows = ni*16*stride).
  const unsigned short* bg1[4];
  const unsigned short* bg2[4];
  float bvv[4][2];
  #pragma unroll
  for (int g=0; g<4; ++g){
    int n = g*Hh + jw + l15;
    bg1[g] = P.Wih + (size_t)n*E  + q*8;
    bg2[g] = P.Whh + (size_t)n*Hh + q*8;
    bvv[g][0] = P.bias[n];
    bvv[g][1] = P.bias[n + 16];
  }

  float cc[16];                    // cell state: [mi][ni][r] -> mi*8+ni*4+r
  #pragma unroll
  for (int i=0;i<16;++i) cc[i] = 0.f;

  for (int t = 0; t < T; ++t){
    const unsigned short* h_in  = P.h0 + (size_t)(t&1)*P.nh;
    unsigned short*       h_out = P.h0 + (size_t)((t+1)&1)*P.nh;

    f32x4 acc[2][4][2];
    #pragma unroll
    for (int i=0;i<2;++i)
      #pragma unroll
      for (int g=0;g<4;++g)
        #pragma unroll
        for (int ni=0;ni<2;++ni) acc[i][g][ni] = (f32x4){0.f,0.f,0.f,0.f};

    // Wait for h(t), then ISSUE the coherent staging loads (16B each) so they
    // fly during phase-1. t==0: h is zeros -> phase 2 skipped entirely.
    uint4v stg[8];
    if (t > 0){
      if (tid == 0){
        unsigned tgt = 4u * (unsigned)t;
        long guard = 0;
        while (__hip_atomic_load(cgp, __ATOMIC_RELAXED, __HIP_MEMORY_SCOPE_AGENT) < tgt){
          __builtin_amdgcn_s_sleep(1);
          if (++guard > 2000000L) break;   // convert protocol bug -> wrong answer, not hang
        }
      }
      __syncthreads();
      asm volatile("" ::: "memory");       // compiler-only fence (no cache ops)

      const unsigned short* base = h_in + (size_t)m0*Hh;
      #pragma unroll
      for (int i=0;i<8;++i){
        int d = (tid + 256*i + (jt<<9)) & 2047;   // per-group rotation, full cover
        const void* ap = (const void*)(base + (size_t)d*8);
        asm volatile("global_load_dwordx4 %0, %1, off sc0 sc1"
                     : "=v"(stg[i]) : "v"(ap) : "memory");
      }
    }

    // Phase 1: K=0..255, x = emb, W = Wih. Staging loads in flight.
    const unsigned short* ap1b[2];
    const float* ap1f[2];
    #pragma unroll
    for (int mi=0; mi<2; ++mi){
      int id = idrow[mi][t];
      if (EBF) ap1b[mi] = P.embb + (size_t)id*E + q*8;
      else     ap1f[mi] = P.emb  + (size_t)id*E + q*8;
    }
    #pragma unroll 2
    for (int kc=0; kc<8; ++kc){
      short8 a[2], b[4][2];
      #pragma unroll
      for (int mi=0;mi<2;++mi){
        if (EBF) a[mi] = *(const short8*)(ap1b[mi] + kc*32);
        else     a[mi] = cvt8(ap1f[mi] + kc*32);
      }
      #pragma unroll
      for (int g=0;g<4;++g)
        #pragma unroll
        for (int ni=0;ni<2;++ni)
          b[g][ni] = *(const short8*)(bg1[g] + ni*16*E + kc*32);
      #pragma unroll
      for (int mi=0;mi<2;++mi)
        #pragma unroll
        for (int g=0;g<4;++g)
          #pragma unroll
          for (int ni=0;ni<2;++ni)
            acc[mi][g][ni] = __builtin_amdgcn_mfma_f32_16x16x32_bf16(a[mi], b[g][ni], acc[mi][g][ni], 0,0,0);
    }

    if (t > 0){
      // Drain staging loads, deposit to swizzled LDS (16B-unit swizzle, proven).
      asm volatile("s_waitcnt vmcnt(0)" ::: "memory");
      #pragma unroll
      for (int i=0;i<8;++i){
        int d = (tid + 256*i + (jt<<9)) & 2047;
        int row = d >> 6, cp = d & 63;
        *(uint4v*)&hs[row][(cp ^ (row & 7)) << 3] = stg[i];
      }
      __syncthreads();

      // Phase 2: K=256..767, x = h (bf16, from swizzled LDS), W = Whh
      #pragma unroll 2
      for (int kc=0; kc<16; ++kc){
        short8 a[2], b[4][2];
        #pragma unroll
        for (int mi=0;mi<2;++mi)
          a[mi] = *(const short8*)&hs[mi*16 + l15][(kc*32 + q*8) ^ xr];
        #pragma unroll
        for (int g=0;g<4;++g)
          #pragma unroll
          for (int ni=0;ni<2;++ni)
            b[g][ni] = *(const short8*)(bg2[g] + ni*16*Hh + kc*32);
        #pragma unroll
        for (int mi=0;mi<2;++mi)
          #pragma unroll
          for (int g=0;g<4;++g)
            #pragma unroll
            for (int ni=0;ni<2;++ni)
              acc[mi][g][ni] = __builtin_amdgcn_mfma_f32_16x16x32_bf16(a[mi], b[g][ni], acc[mi][g][ni], 0,0,0);
      }
    }

    // In-register epilogue: C layout (m89-verified) row=q*4+r, col=l15 -> lane
    // element (mi*16+q*4+r, jw+ni*16+l15) has its 4 gates in acc[mi][g][ni][r].
    #pragma unroll
    for (int mi=0;mi<2;++mi)
      #pragma unroll
      for (int ni=0;ni<2;++ni)
        #pragma unroll
        for (int r=0;r<4;++r){
          float zi = acc[mi][0][ni][r] + bvv[0][ni];
          float zf = acc[mi][1][ni][r] + bvv[1][ni];
          float zg = acc[mi][2][ni][r] + bvv[2][ni];
          float zo = acc[mi][3][ni][r] + bvv[3][ni];
          float cn = sigm(zf)*cc[mi*8+ni*4+r] + sigm(zi)*tanh_f(zg);
          float hn = sigm(zo)*tanh_f(cn);
          cc[mi*8+ni*4+r] = cn;
          sh_h[mi*16 + q*4 + r][w*32 + ni*16 + l15] = f2bf(hn);
        }
    __syncthreads();

    // Shuttle -> two 16B coherent h stores per thread (32 rows x 16 oct-chunks).
    #pragma unroll
    for (int i=0;i<2;++i){
      int idx = tid + 256*i;                  // 0..511
      int m = idx >> 4, oct = idx & 15;
      uint4v pk = *(const uint4v*)&sh_h[m][oct*8];
      void* ap = (void*)(h_out + (size_t)(m0+m)*Hh + j0 + oct*8);
      asm volatile("global_store_dwordx4 %0, %1, off sc0 sc1"
                   :: "v"(ap), "v"(pk) : "memory");
    }

    // Release step t: drain own write-through stores, converge, tid0 counts.
    asm volatile("s_waitcnt vmcnt(0)" ::: "memory");
    __syncthreads();
    if (tid == 0)
      __hip_atomic_fetch_add(cgp, 1u, __ATOMIC_RELAXED, __HIP_MEMORY_SCOPE_AGENT);
  }

  // Final c to global (plain stores; dispatch boundary publishes to out_kernel).
  #pragma unroll
  for (int mi=0;mi<2;++mi)
    #pragma unroll
    for (int ni=0;ni<2;++ni)
      #pragma unroll
      for (int r=0;r<4;++r)
        P.c[(size_t)(m0 + mi*16 + q*4 + r)*Hh + jw + ni*16 + l15] = cc[mi*8+ni*4+r];
}

// Output kernel (R16-proven). 256 blocks: (b, kind, u-half). v-row in LDS,
// hm via shfl-reduce (1 barrier), u-dot with 4 independent accumulators.
__global__ __launch_bounds__(256) void out_kernel(
    const unsigned short* hsc, const unsigned short* hcm, const unsigned short* his,
    const float* csc, const float* ccm, const float* cis,
    const float* Wmh, const float* bmh, const float* Wmc, const float* bmc,
    const float* Wfh, const float* bfh, const float* Wfc, const float* bfc,
    float* out)
{
  const int b    = blockIdx.x >> 2;
  const int kind = (blockIdx.x >> 1) & 1;
  const int half = blockIdx.x & 1;
  const int tid  = threadIdx.x;
  const int w = tid >> 6, lane = tid & 63;
  const float* Wm = kind ? Wmc : Wmh;
  const float* bm = kind ? bmc : bmh;
  const float* Wf = kind ? Wfc : Wfh;
  const float* bf = kind ? bfc : bfh;

  __shared__ float vis[512];
  __shared__ float wred[10][4];
  __shared__ float hmb[10];

  for (int k = tid; k < 512; k += 256)
    vis[k] = kind ? cis[(size_t)b*512 + k] : bf2f(his[(size_t)b*512 + k]);

  float pn[10];
  #pragma unroll
  for (int nc=0; nc<10; ++nc){
    size_t n = (size_t)b*10 + nc;
    float a = 0.f;
    #pragma unroll
    for (int kk=0; kk<2; ++kk){
      int k = tid + kk*256;
      float v1 = kind ? csc[n*512+k] : bf2f(hsc[n*512+k]);
      float v2 = kind ? ccm[n*512+k] : bf2f(hcm[n*512+k]);
      a += Wm[k]*v1 + Wm[512+k]*v2;
    }
    pn[nc] = a;
  }
  #pragma unroll
  for (int nc=0; nc<10; ++nc){
    float v = pn[nc];
    #pragma unroll
    for (int off=32; off; off>>=1) v += __shfl_down(v, off);
    if (lane == 0) wred[nc][w] = v;
  }
  __syncthreads();
  if (tid < 10) hmb[tid] = wred[tid][0] + wred[tid][1] + wred[tid][2] + wred[tid][3] + bm[0];
  __syncthreads();

  const int u = tid + 256*half;
  const float* wr = Wf + (size_t)u*522;
  float a0 = bf[u], a1 = 0.f, a2 = 0.f, a3 = 0.f;
  #pragma unroll
  for (int k=0; k<10; ++k) a0 += wr[k]*hmb[k];
  #pragma unroll 4
  for (int k=0; k<512; k+=4){
    a0 += wr[10+k] * vis[k];
    a1 += wr[11+k] * vis[k+1];
    a2 += wr[12+k] * vis[k+2];
    a3 += wr[13+k] * vis[k+3];
  }
  out[(size_t)kind*32768 + (size_t)b*512 + u] = (a0+a1) + (a2+a3);
}

extern "C" void kernel_launch(void* const* d_in, const int* in_sizes, int n_in,
                              void* d_out, int out_size, void* d_ws, size_t ws_size,
                              hipStream_t stream) {
  const int* comments = (const int*)d_in[0];
  const int* cm_ids   = (const int*)d_in[1];
  const int* issue    = (const int*)d_in[2];
  const float* emb_sc = (const float*)d_in[3];
  const float* emb_cm = (const float*)d_in[4];
  const float* emb_is = (const float*)d_in[5];
  const float* Wih_sc = (const float*)d_in[6];
  const float* Whh_sc = (const float*)d_in[7];
  const float* b_sc   = (const float*)d_in[8];
  const float* Wih_cm = (const float*)d_in[9];
  const float* Whh_cm = (const float*)d_in[10];
  const float* b_cm   = (const float*)d_in[11];
  const float* Wih_is = (const float*)d_in[12];
  const float* Whh_is = (const float*)d_in[13];
  const float* b_is   = (const float*)d_in[14];
  const float* Wmh = (const float*)d_in[15];
  const float* bmh = (const float*)d_in[16];
  const float* Wmc = (const float*)d_in[17];
  const float* bmc = (const float*)d_in[18];
  const float* Wfh = (const float*)d_in[19];
  const float* bfh = (const float*)d_in[20];
  const float* Wfc = (const float*)d_in[21];
  const float* bfc = (const float*)d_in[22];

  // Workspace: R3-proven 14.94 MB layout, optionally extended by bf16 emb tables.
  char* p = (char*)d_ws;
  unsigned short* hb_sc = (unsigned short*)p; p += (size_t)2*640*512*2;
  unsigned short* hb_cm = (unsigned short*)p; p += (size_t)2*640*512*2;
  unsigned short* hb_is = (unsigned short*)p; p += (size_t)2*64*512*2;
  float* c_sc = (float*)p; p += (size_t)640*512*4;
  float* c_cm = (float*)p; p += (size_t)640*512*4;
  float* c_is = (float*)p; p += (size_t)64*512*4;
  size_t zero_bytes = (size_t)(p - (char*)d_ws);
  unsigned short* Wih_sc_b = (unsigned short*)p; p += (size_t)2048*256*2;
  unsigned short* Whh_sc_b = (unsigned short*)p; p += (size_t)2048*512*2;
  unsigned short* Wih_cm_b = (unsigned short*)p; p += (size_t)2048*256*2;
  unsigned short* Whh_cm_b = (unsigned short*)p; p += (size_t)2048*512*2;
  unsigned short* Wih_is_b = (unsigned short*)p; p += (size_t)2048*256*2;
  unsigned short* Whh_is_b = (unsigned short*)p; p += (size_t)2048*512*2;
  // bf16 emb tables (guarded by ws_size)
  const size_t emb_elems = (size_t)32000*256;
  unsigned short* emb_sc_b = (unsigned short*)p; p += emb_elems*2;
  unsigned short* emb_cm_b = (unsigned short*)p; p += emb_elems*2;
  unsigned short* emb_is_b = (unsigned short*)p; p += emb_elems*2;
  size_t need_bf = (size_t)(p - (char*)d_ws);
  const bool ebf = (ws_size >= need_bf);

  int n4 = (int)(zero_bytes/16);
  zero_ws_kernel<<<(n4+255)/256, 256, 0, stream>>>((uint4*)d_ws, n4);
  zero_cnt_kernel<<<1, 256, 0, stream>>>();

  const int nih8 = 2048*256/8, nhh8 = 2048*512/8;
  cvt_kernel<<<(nih8+255)/256, 256, 0, stream>>>(Wih_sc, Wih_sc_b, nih8);
  cvt_kernel<<<(nhh8+255)/256, 256, 0, stream>>>(Whh_sc, Whh_sc_b, nhh8);
  cvt_kernel<<<(nih8+255)/256, 256, 0, stream>>>(Wih_cm, Wih_cm_b, nih8);
  cvt_kernel<<<(nhh8+255)/256, 256, 0, stream>>>(Whh_cm, Whh_cm_b, nhh8);
  cvt_kernel<<<(nih8+255)/256, 256, 0, stream>>>(Wih_is, Wih_is_b, nih8);
  cvt_kernel<<<(nhh8+255)/256, 256, 0, stream>>>(Whh_is, Whh_is_b, nhh8);
  if (ebf){
    const int ne8 = (int)(emb_elems/8);
    cvt_kernel<<<(ne8+255)/256, 256, 0, stream>>>(emb_sc, emb_sc_b, ne8);
    cvt_kernel<<<(ne8+255)/256, 256, 0, stream>>>(emb_cm, emb_cm_b, ne8);
    cvt_kernel<<<(ne8+255)/256, 256, 0, stream>>>(emb_is, emb_is_b, ne8);
  }

  LstmP Psc = { comments, emb_sc, emb_sc_b, Wih_sc_b, Whh_sc_b, b_sc, hb_sc, c_sc, 128, 640*512 };
  LstmP Pcm = { cm_ids,   emb_cm, emb_cm_b, Wih_cm_b, Whh_cm_b, b_cm, hb_cm, c_cm,  64, 640*512 };
  LstmP Pis = { issue,    emb_is, emb_is_b, Wih_is_b, Whh_is_b, b_is, hb_is, c_is,  32,  64*512 };
  if (ebf) lstm_persist<1><<<168, 256, 0, stream>>>(Psc, Pcm, Pis);
  else     lstm_persist<0><<<168, 256, 0, stream>>>(Psc, Pcm, Pis);

  // Final h states in buffer 0 for all three (T even for sc/cm/is).
  out_kernel<<<256, 256, 0, stream>>>(hb_sc, hb_cm, hb_is, c_sc, c_cm, c_is,
                                      Wmh, bmh, Wmc, bmc, Wfh, bfh, Wfc, bfc,
                                      (float*)d_out);
}

// Round 10
// 2650.096 us; speedup vs baseline: 1.3934x; 1.3934x over previous
//
#include <hip/hip_runtime.h>
#include <math.h>

#define E 256
#define Hh 512

typedef __attribute__((ext_vector_type(8))) short short8;
typedef __attribute__((ext_vector_type(4))) float f32x4;
typedef __attribute__((ext_vector_type(4))) unsigned uint4v;

// R22: R21 (VGPR-resident Whh, M=64/j=64, 168 blocks, 1 block/CU) with the
// register-pressure peak cut below the 450 no-spill line: staging in TWO
// batches of 8 dwordx4 (max 8 live = 32 VGPR, was 16 = 64), each batch's
// latency hidden under half of phase-1. R21's crash = ~520-reg peak in the
// (256,1) regime. Weight-residency theory unchanged: Whh slice (64KB/wave =
// 256 VGPR) parked once -> zero recurring Whh traffic; Wih streamed, 21
// blocks/XCD x 128KB = 2.7MB < 4MB L2. All exchange/sync/epilogue components
// verbatim R19/R20-proven.

struct LstmP {
  const int* ids;
  const float* emb;            // f32 embedding table (fallback path)
  const unsigned short* embb;  // bf16 embedding table (fast path)
  const unsigned short* Wih;   // bf16 ws cache [2048,256]
  const unsigned short* Whh;   // bf16 ws cache [2048,512]
  const float* bias;           // f32 [2048]
  unsigned short* h0;          // bf16 double buffer base (2 * nh)
  float* c;                    // f32 [N,512] final-c output
  int T;
  int nh;                      // N*512
};

__device__ unsigned g_cnt[42*32];   // per-group step counters, 128B apart

__device__ __forceinline__ float bf2f(unsigned short x){
  union { unsigned u; float f; } v; v.u = ((unsigned)x) << 16; return v.f;
}
__device__ __forceinline__ unsigned short f2bf(float f){
  union { float f; unsigned u; } v; v.f = f;
  unsigned u = v.u;
  return (unsigned short)((u + 0x7fffu + ((u >> 16) & 1u)) >> 16);
}
__device__ __forceinline__ short8 cvt8(const float* p){
  f32x4 x = *(const f32x4*)p;
  f32x4 y = *(const f32x4*)(p + 4);
  short8 r;
  r[0]=(short)f2bf(x[0]); r[1]=(short)f2bf(x[1]); r[2]=(short)f2bf(x[2]); r[3]=(short)f2bf(x[3]);
  r[4]=(short)f2bf(y[0]); r[5]=(short)f2bf(y[1]); r[6]=(short)f2bf(y[2]); r[7]=(short)f2bf(y[3]);
  return r;
}
// Fast activations (R18-proven): v_exp_f32/v_rcp_f32, ~1e-7/step, << threshold.
__device__ __forceinline__ float sigm(float x){
  return __builtin_amdgcn_rcpf(1.0f + __builtin_amdgcn_exp2f(-1.44269504f*x));
}
__device__ __forceinline__ float tanh_f(float x){
  return 1.0f - 2.0f*__builtin_amdgcn_rcpf(1.0f + __builtin_amdgcn_exp2f(2.88539008f*x));
}

__global__ void zero_ws_kernel(uint4* p, int n){
  int i = blockIdx.x*256 + threadIdx.x;
  if (i < n){ uint4 z; z.x=0u; z.y=0u; z.z=0u; z.w=0u; p[i]=z; }
}

__global__ void zero_cnt_kernel(){
  for (int i = threadIdx.x; i < 42*32; i += 256) g_cnt[i] = 0u;
}

// f32 -> bf16 (RNE), 8 elems/thread. (R3-proven cache bit-match.)
__global__ __launch_bounds__(256) void cvt_kernel(const float* src, unsigned short* dst, int n8){
  int i = blockIdx.x*256 + threadIdx.x;
  if (i < n8){
    *(short8*)(dst + (size_t)i*8) = cvt8(src + (size_t)i*8);
  }
}

// Persistent kernel: block = one (lstm, mb64, jt64) tile for all T steps.
// Whh slice in VGPRs (loaded once). Per step: group wait -> {issue 8 coherent
// h loads -> phase1 kc0..3 -> deposit -> issue 8 -> phase1 kc4..7 -> deposit}
// -> barrier -> phase2 (Whh from VGPR) -> in-register epilogue -> coherent h
// stores -> drain -> barrier -> release.
template<int EBF>
__global__ __launch_bounds__(256, 1) void lstm_persist(LstmP sc, LstmP cm, LstmP is_)
{
  __shared__ unsigned short hs[64][512];   // 64 KB staged h slab (swizzled)
  __shared__ unsigned short sh_h[64][72];  // h shuttle, padded rows (144B, 16B-aligned)

  LstmP P; int tile, grp;
  {
    int idx = blockIdx.x;
    if (idx < 80){ P = sc;  tile = idx;        grp = tile >> 3; }
    else if (idx < 160){ P = cm;  tile = idx - 80;   grp = 20 + (tile >> 3); }
    else { P = is_; tile = idx - 160;  grp = 40 + (tile >> 3); }
  }
  const int tid  = threadIdx.x;
  const int w    = tid >> 6;       // wave = 16-wide j-subslice owner (all 4 gates)
  const int lane = tid & 63;
  const int l15  = lane & 15;
  const int q    = lane >> 4;
  const int mb = tile >> 3, jt = tile & 7;
  const int m0 = mb*64, j0 = jt*64;
  const int jw = j0 + w*16;
  const int T = P.T;
  unsigned* cgp = &g_cnt[grp*32];
  const int xr = (l15 & 7) << 3;   // hs row-XOR swizzle (per-lane const, in shorts)

  const int* idrow[4];             // ids row per A-fragment row
  #pragma unroll
  for (int mi=0; mi<4; ++mi){
    int m = m0 + mi*16 + l15;
    idrow[mi] = P.ids + (size_t)m*T;
  }
  const unsigned short* bg1[4];    // streamed Wih rows: gate g, unit jw+l15
  float bvv[4];
  #pragma unroll
  for (int g=0; g<4; ++g){
    int n = g*Hh + jw + l15;
    bg1[g] = P.Wih + (size_t)n*E + q*8;
    bvv[g] = P.bias[n];
  }

  // Park Whh slice in VGPRs: wb[kc][g], 64 x short8 = 256 VGPR. Static idx only.
  short8 wb[16][4];
  #pragma unroll
  for (int g=0; g<4; ++g){
    const unsigned short* bp = P.Whh + (size_t)(g*Hh + jw + l15)*Hh + q*8;
    #pragma unroll
    for (int kc=0; kc<16; ++kc)
      wb[kc][g] = *(const short8*)(bp + kc*32);
  }

  float cc[16];                    // cell state: [mi][r] -> mi*4+r
  #pragma unroll
  for (int i=0;i<16;++i) cc[i] = 0.f;

  for (int t = 0; t < T; ++t){
    const unsigned short* h_in  = P.h0 + (size_t)(t&1)*P.nh;
    unsigned short*       h_out = P.h0 + (size_t)((t+1)&1)*P.nh;

    f32x4 acc[4][4];
    #pragma unroll
    for (int i=0;i<4;++i)
      #pragma unroll
      for (int g=0;g<4;++g) acc[i][g] = (f32x4){0.f,0.f,0.f,0.f};

    // Wait for h(t). t==0: h is zeros -> staging + phase 2 skipped entirely.
    if (t > 0){
      if (tid == 0){
        unsigned tgt = 8u * (unsigned)t;
        long guard = 0;
        while (__hip_atomic_load(cgp, __ATOMIC_RELAXED, __HIP_MEMORY_SCOPE_AGENT) < tgt){
          __builtin_amdgcn_s_sleep(1);
          if (++guard > 2000000L) break;   // convert protocol bug -> wrong answer, not hang
        }
      }
      __syncthreads();
      asm volatile("" ::: "memory");       // compiler-only fence (no cache ops)
    }

    // Phase-1 A pointers (emb).
    const unsigned short* ap1b[4];
    const float* ap1f[4];
    #pragma unroll
    for (int mi=0; mi<4; ++mi){
      int id = idrow[mi][t];
      if (EBF) ap1b[mi] = P.embb + (size_t)id*E + q*8;
      else     ap1f[mi] = P.emb  + (size_t)id*E + q*8;
    }

    const unsigned short* base = h_in + (size_t)m0*Hh;
    // Two staging batches of 8 x 16B coherent loads; each hidden under half
    // of phase-1 (max 8 live uint4v = 32 VGPR peak).
    #pragma unroll
    for (int half=0; half<2; ++half){
      uint4v stg[8];
      if (t > 0){
        #pragma unroll
        for (int i=0;i<8;++i){
          int d = (tid + 256*(i + 8*half) + (jt<<9)) & 4095;   // rotated, full cover
          const void* ap = (const void*)(base + (size_t)d*8);
          asm volatile("global_load_dwordx4 %0, %1, off sc0 sc1"
                       : "=v"(stg[i]) : "v"(ap) : "memory");
        }
      }
      // Phase 1 half: kc = half*4 .. half*4+3
      #pragma unroll
      for (int kk=0; kk<4; ++kk){
        int kc = half*4 + kk;
        short8 a[4], b[4];
        #pragma unroll
        for (int mi=0;mi<4;++mi){
          if (EBF) a[mi] = *(const short8*)(ap1b[mi] + kc*32);
          else     a[mi] = cvt8(ap1f[mi] + kc*32);
        }
        #pragma unroll
        for (int g=0;g<4;++g) b[g] = *(const short8*)(bg1[g] + kc*32);
        #pragma unroll
        for (int mi=0;mi<4;++mi)
          #pragma unroll
          for (int g=0;g<4;++g)
            acc[mi][g] = __builtin_amdgcn_mfma_f32_16x16x32_bf16(a[mi], b[g], acc[mi][g], 0,0,0);
      }
      if (t > 0){
        // Drain this batch, deposit to swizzled LDS (16B-unit swizzle, proven).
        asm volatile("s_waitcnt vmcnt(0)" ::: "memory");
        #pragma unroll
        for (int i=0;i<8;++i){
          int d = (tid + 256*(i + 8*half) + (jt<<9)) & 4095;
          int row = d >> 6, cp = d & 63;
          *(uint4v*)&hs[row][(cp ^ (row & 7)) << 3] = stg[i];
        }
      }
    }

    if (t > 0){
      __syncthreads();
      // Phase 2: K=256..767, x = h (swizzled LDS), W = Whh (VGPR-resident).
      #pragma unroll
      for (int kc=0; kc<16; ++kc){
        short8 a[4];
        #pragma unroll
        for (int mi=0;mi<4;++mi)
          a[mi] = *(const short8*)&hs[mi*16 + l15][(kc*32 + q*8) ^ xr];
        #pragma unroll
        for (int mi=0;mi<4;++mi)
          #pragma unroll
          for (int g=0;g<4;++g)
            acc[mi][g] = __builtin_amdgcn_mfma_f32_16x16x32_bf16(a[mi], wb[kc][g], acc[mi][g], 0,0,0);
      }
    }

    // In-register epilogue: C layout (m89-verified) row=q*4+r, col=l15 -> lane
    // element (mi*16+q*4+r, jw+l15) has its 4 gates in acc[mi][g][r].
    #pragma unroll
    for (int mi=0;mi<4;++mi)
      #pragma unroll
      for (int r=0;r<4;++r){
        float zi = acc[mi][0][r] + bvv[0];
        float zf = acc[mi][1][r] + bvv[1];
        float zg = acc[mi][2][r] + bvv[2];
        float zo = acc[mi][3][r] + bvv[3];
        float cn = sigm(zf)*cc[mi*4+r] + sigm(zi)*tanh_f(zg);
        float hn = sigm(zo)*tanh_f(cn);
        cc[mi*4+r] = cn;
        sh_h[mi*16 + q*4 + r][w*16 + l15] = f2bf(hn);
      }
    __syncthreads();

    // Shuttle -> two 16B coherent h stores per thread (64 rows x 8 oct-chunks).
    #pragma unroll
    for (int i=0;i<2;++i){
      int idx = tid + 256*i;                  // 0..511
      int m = idx >> 3, oct = idx & 7;
      uint4v pk = *(const uint4v*)&sh_h[m][oct*8];
      void* ap = (void*)(h_out + (size_t)(m0+m)*Hh + j0 + oct*8);
      asm volatile("global_store_dwordx4 %0, %1, off sc0 sc1"
                   :: "v"(ap), "v"(pk) : "memory");
    }

    // Release step t: drain own write-through stores, converge, tid0 counts.
    asm volatile("s_waitcnt vmcnt(0)" ::: "memory");
    __syncthreads();
    if (tid == 0)
      __hip_atomic_fetch_add(cgp, 1u, __ATOMIC_RELAXED, __HIP_MEMORY_SCOPE_AGENT);
  }

  // Final c to global (plain stores; dispatch boundary publishes to out_kernel).
  #pragma unroll
  for (int mi=0;mi<4;++mi)
    #pragma unroll
    for (int r=0;r<4;++r)
      P.c[(size_t)(m0 + mi*16 + q*4 + r)*Hh + jw + l15] = cc[mi*4+r];
}

// Output kernel (R16-proven). 256 blocks: (b, kind, u-half). v-row in LDS,
// hm via shfl-reduce (1 barrier), u-dot with 4 independent accumulators.
__global__ __launch_bounds__(256) void out_kernel(
    const unsigned short* hsc, const unsigned short* hcm, const unsigned short* his,
    const float* csc, const float* ccm, const float* cis,
    const float* Wmh, const float* bmh, const float* Wmc, const float* bmc,
    const float* Wfh, const float* bfh, const float* Wfc, const float* bfc,
    float* out)
{
  const int b    = blockIdx.x >> 2;
  const int kind = (blockIdx.x >> 1) & 1;
  const int half = blockIdx.x & 1;
  const int tid  = threadIdx.x;
  const int w = tid >> 6, lane = tid & 63;
  const float* Wm = kind ? Wmc : Wmh;
  const float* bm = kind ? bmc : bmh;
  const float* Wf = kind ? Wfc : Wfh;
  const float* bf = kind ? bfc : bfh;

  __shared__ float vis[512];
  __shared__ float wred[10][4];
  __shared__ float hmb[10];

  for (int k = tid; k < 512; k += 256)
    vis[k] = kind ? cis[(size_t)b*512 + k] : bf2f(his[(size_t)b*512 + k]);

  float pn[10];
  #pragma unroll
  for (int nc=0; nc<10; ++nc){
    size_t n = (size_t)b*10 + nc;
    float a = 0.f;
    #pragma unroll
    for (int kk=0; kk<2; ++kk){
      int k = tid + kk*256;
      float v1 = kind ? csc[n*512+k] : bf2f(hsc[n*512+k]);
      float v2 = kind ? ccm[n*512+k] : bf2f(hcm[n*512+k]);
      a += Wm[k]*v1 + Wm[512+k]*v2;
    }
    pn[nc] = a;
  }
  #pragma unroll
  for (int nc=0; nc<10; ++nc){
    float v = pn[nc];
    #pragma unroll
    for (int off=32; off; off>>=1) v += __shfl_down(v, off);
    if (lane == 0) wred[nc][w] = v;
  }
  __syncthreads();
  if (tid < 10) hmb[tid] = wred[tid][0] + wred[tid][1] + wred[tid][2] + wred[tid][3] + bm[0];
  __syncthreads();

  const int u = tid + 256*half;
  const float* wr = Wf + (size_t)u*522;
  float a0 = bf[u], a1 = 0.f, a2 = 0.f, a3 = 0.f;
  #pragma unroll
  for (int k=0; k<10; ++k) a0 += wr[k]*hmb[k];
  #pragma unroll 4
  for (int k=0; k<512; k+=4){
    a0 += wr[10+k] * vis[k];
    a1 += wr[11+k] * vis[k+1];
    a2 += wr[12+k] * vis[k+2];
    a3 += wr[13+k] * vis[k+3];
  }
  out[(size_t)kind*32768 + (size_t)b*512 + u] = (a0+a1) + (a2+a3);
}

extern "C" void kernel_launch(void* const* d_in, const int* in_sizes, int n_in,
                              void* d_out, int out_size, void* d_ws, size_t ws_size,
                              hipStream_t stream) {
  const int* comments = (const int*)d_in[0];
  const int* cm_ids   = (const int*)d_in[1];
  const int* issue    = (const int*)d_in[2];
  const float* emb_sc = (const float*)d_in[3];
  const float* emb_cm = (const float*)d_in[4];
  const float* emb_is = (const float*)d_in[5];
  const float* Wih_sc = (const float*)d_in[6];
  const float* Whh_sc = (const float*)d_in[7];
  const float* b_sc   = (const float*)d_in[8];
  const float* Wih_cm = (const float*)d_in[9];
  const float* Whh_cm = (const float*)d_in[10];
  const float* b_cm   = (const float*)d_in[11];
  const float* Wih_is = (const float*)d_in[12];
  const float* Whh_is = (const float*)d_in[13];
  const float* b_is   = (const float*)d_in[14];
  const float* Wmh = (const float*)d_in[15];
  const float* bmh = (const float*)d_in[16];
  const float* Wmc = (const float*)d_in[17];
  const float* bmc = (const float*)d_in[18];
  const float* Wfh = (const float*)d_in[19];
  const float* bfh = (const float*)d_in[20];
  const float* Wfc = (const float*)d_in[21];
  const float* bfc = (const float*)d_in[22];

  // Workspace: R3-proven 14.94 MB layout, optionally extended by bf16 emb tables.
  char* p = (char*)d_ws;
  unsigned short* hb_sc = (unsigned short*)p; p += (size_t)2*640*512*2;
  unsigned short* hb_cm = (unsigned short*)p; p += (size_t)2*640*512*2;
  unsigned short* hb_is = (unsigned short*)p; p += (size_t)2*64*512*2;
  float* c_sc = (float*)p; p += (size_t)640*512*4;
  float* c_cm = (float*)p; p += (size_t)640*512*4;
  float* c_is = (float*)p; p += (size_t)64*512*4;
  size_t zero_bytes = (size_t)(p - (char*)d_ws);
  unsigned short* Wih_sc_b = (unsigned short*)p; p += (size_t)2048*256*2;
  unsigned short* Whh_sc_b = (unsigned short*)p; p += (size_t)2048*512*2;
  unsigned short* Wih_cm_b = (unsigned short*)p; p += (size_t)2048*256*2;
  unsigned short* Whh_cm_b = (unsigned short*)p; p += (size_t)2048*512*2;
  unsigned short* Wih_is_b = (unsigned short*)p; p += (size_t)2048*256*2;
  unsigned short* Whh_is_b = (unsigned short*)p; p += (size_t)2048*512*2;
  // bf16 emb tables (guarded by ws_size)
  const size_t emb_elems = (size_t)32000*256;
  unsigned short* emb_sc_b = (unsigned short*)p; p += emb_elems*2;
  unsigned short* emb_cm_b = (unsigned short*)p; p += emb_elems*2;
  unsigned short* emb_is_b = (unsigned short*)p; p += emb_elems*2;
  size_t need_bf = (size_t)(p - (char*)d_ws);
  const bool ebf = (ws_size >= need_bf);

  int n4 = (int)(zero_bytes/16);
  zero_ws_kernel<<<(n4+255)/256, 256, 0, stream>>>((uint4*)d_ws, n4);
  zero_cnt_kernel<<<1, 256, 0, stream>>>();

  const int nih8 = 2048*256/8, nhh8 = 2048*512/8;
  cvt_kernel<<<(nih8+255)/256, 256, 0, stream>>>(Wih_sc, Wih_sc_b, nih8);
  cvt_kernel<<<(nhh8+255)/256, 256, 0, stream>>>(Whh_sc, Whh_sc_b, nhh8);
  cvt_kernel<<<(nih8+255)/256, 256, 0, stream>>>(Wih_cm, Wih_cm_b, nih8);
  cvt_kernel<<<(nhh8+255)/256, 256, 0, stream>>>(Whh_cm, Whh_cm_b, nhh8);
  cvt_kernel<<<(nih8+255)/256, 256, 0, stream>>>(Wih_is, Wih_is_b, nih8);
  cvt_kernel<<<(nhh8+255)/256, 256, 0, stream>>>(Whh_is, Whh_is_b, nhh8);
  if (ebf){
    const int ne8 = (int)(emb_elems/8);
    cvt_kernel<<<(ne8+255)/256, 256, 0, stream>>>(emb_sc, emb_sc_b, ne8);
    cvt_kernel<<<(ne8+255)/256, 256, 0, stream>>>(emb_cm, emb_cm_b, ne8);
    cvt_kernel<<<(ne8+255)/256, 256, 0, stream>>>(emb_is, emb_is_b, ne8);
  }

  LstmP Psc = { comments, emb_sc, emb_sc_b, Wih_sc_b, Whh_sc_b, b_sc, hb_sc, c_sc, 128, 640*512 };
  LstmP Pcm = { cm_ids,   emb_cm, emb_cm_b, Wih_cm_b, Whh_cm_b, b_cm, hb_cm, c_cm,  64, 640*512 };
  LstmP Pis = { issue,    emb_is, emb_is_b, Wih_is_b, Whh_is_b, b_is, hb_is, c_is,  32,  64*512 };
  if (ebf) lstm_persist<1><<<168, 256, 0, stream>>>(Psc, Pcm, Pis);
  else     lstm_persist<0><<<168, 256, 0, stream>>>(Psc, Pcm, Pis);

  // Final h states in buffer 0 for all three (T even for sc/cm/is).
  out_kernel<<<256, 256, 0, stream>>>(hb_sc, hb_cm, hb_is, c_sc, c_cm, c_is,
                                      Wmh, bmh, Wmc, bmc, Wfh, bfh, Wfc, bfc,
                                      (float*)d_out);
}